// Round 2
// baseline (106.861 us; speedup 1.0000x reference)
//
#include <hip/hip_runtime.h>
#include <hip/hip_bf16.h>

typedef __attribute__((ext_vector_type(4))) float f32x4;

#define TPB 256

// ---- ws layout (float offsets) ----
#define IN1F   0
#define IN2F   1120
#define HN1F   2240
#define HN2F   4288
#define L1OUT  6336
#define L3OUT  11456
#define GH1    16576
#define GH2    22720
#define GI1    28864
#define GI2    35008
#define H1OFF  41152
#define H2OFF  43200
#define T1OFF  45248
#define T2OFF  49344
// total 53440 floats = 213,760 bytes

// One block: stage x[0:K] (f32) into LDS, then 4 waves each compute
// rowsPerWave rows of y = act(W @ x + b). K % 4 == 0.
__device__ __forceinline__ void matvec_block(
    const float* __restrict__ W,
    const float* __restrict__ bias,
    const float* __restrict__ x, float* xl, int K,
    int row0, int rowsPerWave, float* __restrict__ y, int act)
{
    // cooperative stage of x into LDS (f32x4)
    for (int i = threadIdx.x; i < (K >> 2); i += TPB)
        ((f32x4*)xl)[i] = ((const f32x4*)x)[i];
    __syncthreads();

    const int wid  = threadIdx.x >> 6;
    const int lane = threadIdx.x & 63;
    const int c0   = lane * 4;

    int r = row0 + wid * rowsPerWave;
    for (int i = 0; i < rowsPerWave; ++i, ++r) {
        const float* Wr = W + (size_t)r * K;
        float acc = 0.f;
        for (int kc = 0; kc < K; kc += 256) {
            int c = kc + c0;
            if (c < K) {
                const f32x4 w4 = *reinterpret_cast<const f32x4*>(Wr + c);
                const f32x4 xv = *reinterpret_cast<const f32x4*>(xl + c);
                acc += w4[0] * xv[0] + w4[1] * xv[1]
                     + w4[2] * xv[2] + w4[3] * xv[3];
            }
        }
#pragma unroll
        for (int off = 32; off; off >>= 1) acc += __shfl_xor(acc, off, 64);
        if (lane == 0) {
            float v = acc + bias[r];
            if (act) v = fmaxf(v, 0.f);
            y[r] = v;
        }
    }
}

// ---- stage 0: build input1/input2 + copy hn ----
__global__ void k_prep(const float* __restrict__ state_inno,
                       const float* __restrict__ obs_inno,
                       const float* __restrict__ diff_state,
                       const float* __restrict__ diff_obs,
                       const float* __restrict__ lin_err,
                       const float* __restrict__ jac,
                       const float* __restrict__ hn1,
                       const float* __restrict__ hn2,
                       float* __restrict__ ws)
{
    int i = blockIdx.x * blockDim.x + threadIdx.x;
    if (i < 1120) {
        float v;
        if (i < 32)       v = state_inno[i];
        else if (i < 64)  v = diff_state[i - 32];
        else if (i < 96)  v = lin_err[i - 64];
        else              v = jac[i - 96];
        ws[IN1F + i] = v;
        float v2;
        if (i < 32)       v2 = obs_inno[i];
        else if (i < 64)  v2 = diff_obs[i - 32];
        else              v2 = v;  // lin_err / jacobian shared
        ws[IN2F + i] = v2;
    }
    if (i < 2048) {
        ws[HN1F + i] = hn1[i];
        ws[HN2F + i] = hn2[i];
    }
}

// ---- stage A: l1, l3 (5120x1120, relu) + Whh@hn (6144x2048) x2 ----
__global__ void __launch_bounds__(TPB)
k_stageA(const float* l1_W, const float* l1_b,
         const float* l3_W, const float* l3_b,
         const float* Whh1, const float* bhh1,
         const float* Whh2, const float* bhh2,
         float* ws)
{
    __shared__ float xl[2048];
    int bid = blockIdx.x;
    if (bid < 320)
        matvec_block(l1_W, l1_b, ws + IN1F, xl, 1120, bid * 16, 4, ws + L1OUT, 1);
    else if (bid < 640)
        matvec_block(l3_W, l3_b, ws + IN2F, xl, 1120, (bid - 320) * 16, 4, ws + L3OUT, 1);
    else if (bid < 1024)
        matvec_block(Whh1, bhh1, ws + HN1F, xl, 2048, (bid - 640) * 16, 4, ws + GH1, 0);
    else
        matvec_block(Whh2, bhh2, ws + HN2F, xl, 2048, (bid - 1024) * 16, 4, ws + GH2, 0);
}

// ---- stage B: Wih @ l_out (6144x5120) x2 ----
__global__ void __launch_bounds__(TPB)
k_stageB(const float* Wih1, const float* bih1,
         const float* Wih2, const float* bih2,
         float* ws)
{
    __shared__ float xl[5120];
    int bid = blockIdx.x;
    if (bid < 384)
        matvec_block(Wih1, bih1, ws + L1OUT, xl, 5120, bid * 16, 4, ws + GI1, 0);
    else
        matvec_block(Wih2, bih2, ws + L3OUT, xl, 5120, (bid - 384) * 16, 4, ws + GI2, 0);
}

// ---- stage C: GRU gate combine (both branches) ----
__global__ void k_gru(const float* __restrict__ hn1,
                      const float* __restrict__ hn2,
                      float* __restrict__ ws)
{
    int i = blockIdx.x * blockDim.x + threadIdx.x;  // 0..4095
    int b = i >> 11, j = i & 2047;
    const float* gi = ws + (b ? GI2 : GI1);
    const float* gh = ws + (b ? GH2 : GH1);
    const float* hn = b ? hn2 : hn1;
    float r = 1.f / (1.f + expf(-(gi[j] + gh[j])));
    float z = 1.f / (1.f + expf(-(gi[2048 + j] + gh[2048 + j])));
    float n = tanhf(gi[4096 + j] + r * gh[4096 + j]);
    float h = (1.f - z) * n + z * hn[j];
    ws[(b ? H2OFF : H1OFF) + j] = h;
}

// ---- stage D: l2_W1 / l4_W1 (4096x2048, relu) ----
__global__ void __launch_bounds__(TPB)
k_stageD(const float* W21, const float* b21,
         const float* W41, const float* b41,
         float* ws)
{
    __shared__ float xl[2048];
    int bid = blockIdx.x;
    if (bid < 256)
        matvec_block(W21, b21, ws + H1OFF, xl, 2048, bid * 16, 4, ws + T1OFF, 1);
    else
        matvec_block(W41, b41, ws + H2OFF, xl, 2048, (bid - 256) * 16, 4, ws + T2OFF, 1);
}

// ---- stage E: l2_W2 / l4_W2 (1024x4096) -> f32 out ----
__global__ void __launch_bounds__(TPB)
k_stageE(const float* W22, const float* b22,
         const float* W42, const float* b42,
         float* ws, float* out)
{
    __shared__ float xl[4096];
    int bid = blockIdx.x;
    if (bid < 128)
        matvec_block(W22, b22, ws + T1OFF, xl, 4096, bid * 8, 2, out, 0);
    else
        matvec_block(W42, b42, ws + T2OFF, xl, 4096, (bid - 128) * 8, 2, out + 1024, 0);
}

extern "C" void kernel_launch(void* const* d_in, const int* in_sizes, int n_in,
                              void* d_out, int out_size, void* d_ws, size_t ws_size,
                              hipStream_t stream)
{
    const float* state_inno = (const float*)d_in[0];
    const float* obs_inno   = (const float*)d_in[1];
    const float* diff_state = (const float*)d_in[2];
    const float* diff_obs   = (const float*)d_in[3];
    const float* lin_err    = (const float*)d_in[4];
    const float* jac        = (const float*)d_in[5];
    const float* l1_W  = (const float*)d_in[6];
    const float* l1_b  = (const float*)d_in[7];
    const float* g1Wih = (const float*)d_in[8];
    const float* g1Whh = (const float*)d_in[9];
    const float* g1bih = (const float*)d_in[10];
    const float* g1bhh = (const float*)d_in[11];
    const float* l2_W1 = (const float*)d_in[12];
    const float* l2_b1 = (const float*)d_in[13];
    const float* l2_W2 = (const float*)d_in[14];
    const float* l2_b2 = (const float*)d_in[15];
    const float* l3_W  = (const float*)d_in[16];
    const float* l3_b  = (const float*)d_in[17];
    const float* g2Wih = (const float*)d_in[18];
    const float* g2Whh = (const float*)d_in[19];
    const float* g2bih = (const float*)d_in[20];
    const float* g2bhh = (const float*)d_in[21];
    const float* l4_W1 = (const float*)d_in[22];
    const float* l4_b1 = (const float*)d_in[23];
    const float* l4_W2 = (const float*)d_in[24];
    const float* l4_b2 = (const float*)d_in[25];
    const float* hn1   = (const float*)d_in[26];
    const float* hn2   = (const float*)d_in[27];

    float* ws = (float*)d_ws;
    float* out = (float*)d_out;

    hipLaunchKernelGGL(k_prep, dim3(8), dim3(TPB), 0, stream,
                       state_inno, obs_inno, diff_state, diff_obs, lin_err, jac,
                       hn1, hn2, ws);

    hipLaunchKernelGGL(k_stageA, dim3(1408), dim3(TPB), 0, stream,
                       l1_W, l1_b, l3_W, l3_b, g1Whh, g1bhh, g2Whh, g2bhh, ws);

    hipLaunchKernelGGL(k_stageB, dim3(768), dim3(TPB), 0, stream,
                       g1Wih, g1bih, g2Wih, g2bih, ws);

    hipLaunchKernelGGL(k_gru, dim3(16), dim3(TPB), 0, stream, hn1, hn2, ws);

    hipLaunchKernelGGL(k_stageD, dim3(512), dim3(TPB), 0, stream,
                       l2_W1, l2_b1, l4_W1, l4_b1, ws);

    hipLaunchKernelGGL(k_stageE, dim3(256), dim3(TPB), 0, stream,
                       l2_W2, l2_b2, l4_W2, l4_b2, ws, out);
}

// Round 3
// 104.036 us; speedup vs baseline: 1.0272x; 1.0272x over previous
//
#include <hip/hip_runtime.h>
#include <hip/hip_bf16.h>

typedef __attribute__((ext_vector_type(4))) float f32x4;

#define TPB 256

// ---- ws layout (float offsets) ----
#define IN1F   0
#define IN2F   1120
#define HN1F   2240
#define HN2F   4288
#define L1OUT  6336
#define L3OUT  11456
#define GH1    16576
#define GH2    22720
#define GI1    28864
#define GI2    35008
#define H1OFF  41152
#define H2OFF  43200
#define T1OFF  45248
#define T2OFF  49344
// total 53440 floats = 213,760 bytes

// One block: stage x[0:K] (f32) into LDS, then 4 waves each compute NR rows
// CONCURRENTLY (independent acc chains -> NR loads in flight per kc step).
// Block covers 4*NR consecutive rows. K % 4 == 0; K is a compile-time literal
// at every call site (inlined), so the kc loop fully unrolls.
template <int NR>
__device__ __forceinline__ void matvec_block(
    const float* __restrict__ W,
    const float* __restrict__ bias,
    const float* __restrict__ x, float* xl, int K,
    int row0, float* __restrict__ y, int act)
{
    for (int i = threadIdx.x; i < (K >> 2); i += TPB)
        ((f32x4*)xl)[i] = ((const f32x4*)x)[i];
    __syncthreads();

    const int wid  = threadIdx.x >> 6;
    const int lane = threadIdx.x & 63;
    const int c0   = lane * 4;
    const int r0   = row0 + wid * NR;

    float acc[NR];
#pragma unroll
    for (int j = 0; j < NR; ++j) acc[j] = 0.f;

    for (int kc = 0; kc < K; kc += 256) {
        int c = kc + c0;
        if (c < K) {
            const f32x4 xv = *reinterpret_cast<const f32x4*>(xl + c);
#pragma unroll
            for (int j = 0; j < NR; ++j) {
                const f32x4 w4 =
                    *reinterpret_cast<const f32x4*>(W + (size_t)(r0 + j) * K + c);
                acc[j] += w4[0] * xv[0] + w4[1] * xv[1]
                        + w4[2] * xv[2] + w4[3] * xv[3];
            }
        }
    }
#pragma unroll
    for (int j = 0; j < NR; ++j) {
#pragma unroll
        for (int off = 32; off; off >>= 1) acc[j] += __shfl_xor(acc[j], off, 64);
    }
    if (lane == 0) {
#pragma unroll
        for (int j = 0; j < NR; ++j) {
            float v = acc[j] + bias[r0 + j];
            if (act) v = fmaxf(v, 0.f);
            y[r0 + j] = v;
        }
    }
}

// ---- stage 0: build input1/input2 + copy hn ----
__global__ void k_prep(const float* __restrict__ state_inno,
                       const float* __restrict__ obs_inno,
                       const float* __restrict__ diff_state,
                       const float* __restrict__ diff_obs,
                       const float* __restrict__ lin_err,
                       const float* __restrict__ jac,
                       const float* __restrict__ hn1,
                       const float* __restrict__ hn2,
                       float* __restrict__ ws)
{
    int i = blockIdx.x * blockDim.x + threadIdx.x;
    if (i < 1120) {
        float v;
        if (i < 32)       v = state_inno[i];
        else if (i < 64)  v = diff_state[i - 32];
        else if (i < 96)  v = lin_err[i - 64];
        else              v = jac[i - 96];
        ws[IN1F + i] = v;
        float v2;
        if (i < 32)       v2 = obs_inno[i];
        else if (i < 64)  v2 = diff_obs[i - 32];
        else              v2 = v;  // lin_err / jacobian shared
        ws[IN2F + i] = v2;
    }
    if (i < 2048) {
        ws[HN1F + i] = hn1[i];
        ws[HN2F + i] = hn2[i];
    }
}

// ---- stage A: l1, l3 (5120x1120, relu) + Whh@hn (6144x2048) x2 ----
// 8 rows/block: grid = 640 + 640 + 768 + 768 = 2816
__global__ void __launch_bounds__(TPB)
k_stageA(const float* l1_W, const float* l1_b,
         const float* l3_W, const float* l3_b,
         const float* Whh1, const float* bhh1,
         const float* Whh2, const float* bhh2,
         float* ws)
{
    __shared__ float xl[2048];
    int bid = blockIdx.x;
    if (bid < 640)
        matvec_block<2>(l1_W, l1_b, ws + IN1F, xl, 1120, bid * 8, ws + L1OUT, 1);
    else if (bid < 1280)
        matvec_block<2>(l3_W, l3_b, ws + IN2F, xl, 1120, (bid - 640) * 8, ws + L3OUT, 1);
    else if (bid < 2048)
        matvec_block<2>(Whh1, bhh1, ws + HN1F, xl, 2048, (bid - 1280) * 8, ws + GH1, 0);
    else
        matvec_block<2>(Whh2, bhh2, ws + HN2F, xl, 2048, (bid - 2048) * 8, ws + GH2, 0);
}

// ---- stage B: Wih @ l_out (6144x5120) x2 ----
// 8 rows/block: grid = 768 + 768 = 1536 (6 blocks/CU, 120KB LDS/CU)
__global__ void __launch_bounds__(TPB)
k_stageB(const float* Wih1, const float* bih1,
         const float* Wih2, const float* bih2,
         float* ws)
{
    __shared__ float xl[5120];
    int bid = blockIdx.x;
    if (bid < 768)
        matvec_block<2>(Wih1, bih1, ws + L1OUT, xl, 5120, bid * 8, ws + GI1, 0);
    else
        matvec_block<2>(Wih2, bih2, ws + L3OUT, xl, 5120, (bid - 768) * 8, ws + GI2, 0);
}

// ---- stage C: GRU gate combine (both branches) ----
__global__ void k_gru(const float* __restrict__ hn1,
                      const float* __restrict__ hn2,
                      float* __restrict__ ws)
{
    int i = blockIdx.x * blockDim.x + threadIdx.x;  // 0..4095
    int b = i >> 11, j = i & 2047;
    const float* gi = ws + (b ? GI2 : GI1);
    const float* gh = ws + (b ? GH2 : GH1);
    const float* hn = b ? hn2 : hn1;
    float r = 1.f / (1.f + expf(-(gi[j] + gh[j])));
    float z = 1.f / (1.f + expf(-(gi[2048 + j] + gh[2048 + j])));
    float n = tanhf(gi[4096 + j] + r * gh[4096 + j]);
    float h = (1.f - z) * n + z * hn[j];
    ws[(b ? H2OFF : H1OFF) + j] = h;
}

// ---- stage D: l2_W1 / l4_W1 (4096x2048, relu) ----
// 8 rows/block: grid = 512 + 512 = 1024
__global__ void __launch_bounds__(TPB)
k_stageD(const float* W21, const float* b21,
         const float* W41, const float* b41,
         float* ws)
{
    __shared__ float xl[2048];
    int bid = blockIdx.x;
    if (bid < 512)
        matvec_block<2>(W21, b21, ws + H1OFF, xl, 2048, bid * 8, ws + T1OFF, 1);
    else
        matvec_block<2>(W41, b41, ws + H2OFF, xl, 2048, (bid - 512) * 8, ws + T2OFF, 1);
}

// ---- stage E: l2_W2 / l4_W2 (1024x4096) -> f32 out ----
// One ROW per block; 4 waves split K=4096 into quarters; x read straight
// from L2 (hot 16KB vector); LDS-combine of the 4 partials. grid = 2048.
__global__ void __launch_bounds__(TPB)
k_stageE(const float* __restrict__ W22, const float* __restrict__ b22,
         const float* __restrict__ W42, const float* __restrict__ b42,
         const float* __restrict__ ws, float* __restrict__ out)
{
    __shared__ float part[4];
    int r = blockIdx.x;  // 0..2047
    const float* W; const float* b; const float* x; int rr;
    if (r < 1024) { W = W22; b = b22; x = ws + T1OFF; rr = r; }
    else          { W = W42; b = b42; x = ws + T2OFF; rr = r - 1024; }

    const int wid  = threadIdx.x >> 6;
    const int lane = threadIdx.x & 63;
    const float* Wr = W + (size_t)rr * 4096 + wid * 1024;
    const float* xw = x + wid * 1024;
    const int c0 = lane * 4;

    float acc = 0.f;
#pragma unroll
    for (int kc = 0; kc < 1024; kc += 256) {
        const f32x4 w4 = *reinterpret_cast<const f32x4*>(Wr + kc + c0);
        const f32x4 xv = *reinterpret_cast<const f32x4*>(xw + kc + c0);
        acc += w4[0] * xv[0] + w4[1] * xv[1] + w4[2] * xv[2] + w4[3] * xv[3];
    }
#pragma unroll
    for (int off = 32; off; off >>= 1) acc += __shfl_xor(acc, off, 64);
    if (lane == 0) part[wid] = acc;
    __syncthreads();
    if (threadIdx.x == 0)
        out[r] = part[0] + part[1] + part[2] + part[3] + b[rr];
}

extern "C" void kernel_launch(void* const* d_in, const int* in_sizes, int n_in,
                              void* d_out, int out_size, void* d_ws, size_t ws_size,
                              hipStream_t stream)
{
    const float* state_inno = (const float*)d_in[0];
    const float* obs_inno   = (const float*)d_in[1];
    const float* diff_state = (const float*)d_in[2];
    const float* diff_obs   = (const float*)d_in[3];
    const float* lin_err    = (const float*)d_in[4];
    const float* jac        = (const float*)d_in[5];
    const float* l1_W  = (const float*)d_in[6];
    const float* l1_b  = (const float*)d_in[7];
    const float* g1Wih = (const float*)d_in[8];
    const float* g1Whh = (const float*)d_in[9];
    const float* g1bih = (const float*)d_in[10];
    const float* g1bhh = (const float*)d_in[11];
    const float* l2_W1 = (const float*)d_in[12];
    const float* l2_b1 = (const float*)d_in[13];
    const float* l2_W2 = (const float*)d_in[14];
    const float* l2_b2 = (const float*)d_in[15];
    const float* l3_W  = (const float*)d_in[16];
    const float* l3_b  = (const float*)d_in[17];
    const float* g2Wih = (const float*)d_in[18];
    const float* g2Whh = (const float*)d_in[19];
    const float* g2bih = (const float*)d_in[20];
    const float* g2bhh = (const float*)d_in[21];
    const float* l4_W1 = (const float*)d_in[22];
    const float* l4_b1 = (const float*)d_in[23];
    const float* l4_W2 = (const float*)d_in[24];
    const float* l4_b2 = (const float*)d_in[25];
    const float* hn1   = (const float*)d_in[26];
    const float* hn2   = (const float*)d_in[27];

    float* ws = (float*)d_ws;
    float* out = (float*)d_out;

    hipLaunchKernelGGL(k_prep, dim3(8), dim3(TPB), 0, stream,
                       state_inno, obs_inno, diff_state, diff_obs, lin_err, jac,
                       hn1, hn2, ws);

    hipLaunchKernelGGL(k_stageA, dim3(2816), dim3(TPB), 0, stream,
                       l1_W, l1_b, l3_W, l3_b, g1Whh, g1bhh, g2Whh, g2bhh, ws);

    hipLaunchKernelGGL(k_stageB, dim3(1536), dim3(TPB), 0, stream,
                       g1Wih, g1bih, g2Wih, g2bih, ws);

    hipLaunchKernelGGL(k_gru, dim3(16), dim3(TPB), 0, stream, hn1, hn2, ws);

    hipLaunchKernelGGL(k_stageD, dim3(1024), dim3(TPB), 0, stream,
                       l2_W1, l2_b1, l4_W1, l4_b1, ws);

    hipLaunchKernelGGL(k_stageE, dim3(2048), dim3(TPB), 0, stream,
                       l2_W2, l2_b2, l4_W2, l4_b2, ws, out);
}